// Round 1
// baseline (494.941 us; speedup 1.0000x reference)
//
#include <hip/hip_runtime.h>

#define N_NODES 100000
#define N_EDGES 3200000
#define N_FEAT  256
#define N_HID   64

// ---------------------------------------------------------------------------
// Kernel 1: W_comb[f] = sum_k W_gnn[f,k] * W_cls[k];  bias_y = b_gnn.W_cls + b_cls
// ---------------------------------------------------------------------------
__global__ void k_wcomb(const float* __restrict__ Wg, const float* __restrict__ bg,
                        const float* __restrict__ Wc, const float* __restrict__ bc,
                        float* __restrict__ wcomb, float* __restrict__ biasy) {
    int f = threadIdx.x;  // 256 threads, one per input feature
    float s = 0.f;
#pragma unroll
    for (int k = 0; k < N_HID; ++k) s += Wg[f * N_HID + k] * Wc[k];
    wcomb[f] = s;
    if (f == 0) {
        float b = 0.f;
        for (int k = 0; k < N_HID; ++k) b += bg[k] * Wc[k];
        *biasy = b + bc[0];
    }
}

// ---------------------------------------------------------------------------
// Kernel 2: in-degree over targets (self-loop added later as +1)
// ---------------------------------------------------------------------------
__global__ void k_deg(const int* __restrict__ col, int* __restrict__ deg) {
    int e = blockIdx.x * blockDim.x + threadIdx.x;
    if (e < N_EDGES) atomicAdd(&deg[col[e]], 1);
}

// ---------------------------------------------------------------------------
// Kernel 3: wave-per-node dual dot product.
//   p = x[i].W_est, q = x[i].W_comb
//   dinv[i]  = rsqrt(deg+1)
//   table[i] = {dinv*q, dinv*p}      (gather table for edge pass)
//   acc[i]   = table[i]              (self-loop term pre-added)
// ---------------------------------------------------------------------------
__global__ void k_pqtable(const float* __restrict__ x, const float* __restrict__ West,
                          const float* __restrict__ wcomb, const int* __restrict__ deg,
                          float* __restrict__ dinv, float2* __restrict__ table,
                          float2* __restrict__ acc) {
    int node = (blockIdx.x * blockDim.x + threadIdx.x) >> 6;
    int lane = threadIdx.x & 63;
    if (node >= N_NODES) return;

    float4 v  = ((const float4*)(x + (size_t)node * N_FEAT))[lane];
    float4 we = ((const float4*)West)[lane];
    float4 wc = ((const float4*)wcomb)[lane];

    float ps = v.x * we.x + v.y * we.y + v.z * we.z + v.w * we.w;
    float qs = v.x * wc.x + v.y * wc.y + v.z * wc.z + v.w * wc.w;

#pragma unroll
    for (int off = 32; off > 0; off >>= 1) {
        ps += __shfl_down(ps, off);
        qs += __shfl_down(qs, off);
    }
    if (lane == 0) {
        float di = rsqrtf((float)(deg[node] + 1));
        float2 t = make_float2(di * qs, di * ps);  // .x = y-path, .y = s-path
        dinv[node]  = di;
        table[node] = t;
        acc[node]   = t;
    }
}

// ---------------------------------------------------------------------------
// Kernel 4: per-edge gather + scatter-add.  acc[c] += table[r]
// (dinv[c] factor applied in finalize)
// ---------------------------------------------------------------------------
__global__ void k_edge(const int* __restrict__ ei, const float2* __restrict__ table,
                       float2* __restrict__ acc) {
    int e = blockIdx.x * blockDim.x + threadIdx.x;
    if (e >= N_EDGES) return;
    int r = ei[e];
    int c = ei[N_EDGES + e];
    float2 t = table[r];
    atomicAdd(&acc[c].x, t.x);
    atomicAdd(&acc[c].y, t.y);
}

// ---------------------------------------------------------------------------
// Kernel 5: finalize.  y = dinv*acc.x + bias_y ; s = dinv*acc.y + b_est
// d_out layout: [y (N floats)] [s (N floats)]  (reference returns (y, s))
// ---------------------------------------------------------------------------
__global__ void k_fin(const float* __restrict__ dinv, const float2* __restrict__ acc,
                      const float* __restrict__ biasy, const float* __restrict__ best,
                      float* __restrict__ out) {
    int i = blockIdx.x * blockDim.x + threadIdx.x;
    if (i >= N_NODES) return;
    float di = dinv[i];
    float2 a = acc[i];
    out[i]           = di * a.x + biasy[0];
    out[N_NODES + i] = di * a.y + best[0];
}

extern "C" void kernel_launch(void* const* d_in, const int* in_sizes, int n_in,
                              void* d_out, int out_size, void* d_ws, size_t ws_size,
                              hipStream_t stream) {
    const int*   ei   = (const int*)d_in[0];    // [2, E] row-major: [0:E]=src, [E:2E]=dst
    const float* x    = (const float*)d_in[1];  // [N, 256]
    const float* West = (const float*)d_in[2];  // [256, 1]
    const float* best = (const float*)d_in[3];  // [1]
    const float* Wg   = (const float*)d_in[4];  // [256, 64]
    const float* bg   = (const float*)d_in[5];  // [64]
    const float* Wc   = (const float*)d_in[6];  // [64, 1]
    const float* bc   = (const float*)d_in[7];  // [1]
    float* out = (float*)d_out;

    // workspace layout (all offsets 8B-aligned)
    float*  wcomb = (float*)d_ws;            // 256 f
    float*  biasy = wcomb + 256;             // 1 f
    int*    deg   = (int*)(wcomb + 512);     // N i32  @ byte 2048
    float*  dinv  = (float*)(deg + N_NODES); // N f    @ byte 402048
    float2* table = (float2*)(dinv + N_NODES); // N f2 @ byte 802048
    float2* acc   = table + N_NODES;           // N f2 @ byte 1602048

    hipMemsetAsync(deg, 0, N_NODES * sizeof(int), stream);
    k_wcomb<<<1, 256, 0, stream>>>(Wg, bg, Wc, bc, wcomb, biasy);
    k_deg<<<(N_EDGES + 255) / 256, 256, 0, stream>>>(ei + N_EDGES, deg);
    k_pqtable<<<(N_NODES * 64 + 255) / 256, 256, 0, stream>>>(x, West, wcomb, deg,
                                                              dinv, table, acc);
    k_edge<<<(N_EDGES + 255) / 256, 256, 0, stream>>>(ei, table, acc);
    k_fin<<<(N_NODES + 255) / 256, 256, 0, stream>>>(dinv, acc, biasy, best, out);
}